// Round 20
// baseline (123.921 us; speedup 1.0000x reference)
//
#include <hip/hip_runtime.h>
#include <hip/hip_bf16.h>

#define M_ 2
#define D_ 128
#define NI_ 131072
#define L_ 4
#define NPL_ 2048
#define R_ 8
#define T_ 32
#define N_ (NI_ + L_ * NPL_)   // 139264
#define ND_ (L_ * NPL_)        // 8192 deriv nodes
#define PSTRIDE_ 1792          // per-model partial stride (floats)
#define PUSED_ 1665            // 128 init + 640 fast + 1 posneg + 512 slow (rest zero)
#define FCAP_ 1280             // fast rows capacity per rule (exp ~979)
#define SCAP_ 512              // slow rows capacity total    (exp ~368)
#define CCAP_ 16               // ancestor-closure cap (max possible 15)
#define WSL_ 1176              // per-wave LDS slab (floats): 18 ilist + 128 hbuf + 1024 cache

typedef __bf16 bf16x8 __attribute__((ext_vector_type(8)));
typedef float f32x4 __attribute__((ext_vector_type(4)));

// ---- ws layout (bytes) ----
#define OFF_W2T    0u            // [M][R][128(e)][128(d)] bf16 = 524288
#define OFF_WE1T   524288u       // [M][128(e)][128(d)] bf16    = 65536
#define OFF_TAB    589824u       // [M][T][128] bf16            = 16384
#define OFF_SVEC   606208u       // [M][128] bf16               = 512
#define OFF_EA2    606720u       // [M][64][32][2] f32          = 32768
#define OFF_EWB    639488u       // [M][128][2] f32             = 2048
#define OFF_PA     641536u       // [2][1792] f32 (pA..pTn contiguous 71680 B)
#define OFF_PB     655872u
#define OFF_PPOK   670208u
#define OFF_PNOK   684544u
#define OFF_PTP    698880u       // [1792] f32
#define OFF_PTN    706048u       // end 713216
#define OFF_G      713216u       // [M][R][2][33][128] f32 = 540672 (b1 folded slot-a t<32)
#define OFF_FLIST  1253888u      // [8][1280] int = 40960
#define OFF_SLIST  1294848u      // [512] int = 2048
#define OFF_CFG    1296896u      // [12] int (0..7 fast counts, 8 slow count)

__device__ __forceinline__ unsigned short f2bu(float f) {
  unsigned int u = __float_as_uint(f);
  u += 0x7fffu + ((u >> 16) & 1u);        // RNE (finite values only)
  return (unsigned short)(u >> 16);
}
__device__ __forceinline__ float bfu2f(unsigned short u) {
  return __uint_as_float((unsigned int)u << 16);
}
__device__ __forceinline__ bf16x8 ldb8(const unsigned short* p) {
  return *reinterpret_cast<const bf16x8*>(p);
}
#define WAVE_FENCE() do { \
  asm volatile("s_waitcnt lgkmcnt(0)" ::: "memory"); \
  __builtin_amdgcn_sched_barrier(0); \
} while (0)

// ================= mega-prep (batched: 249 blocks) =================
// jobs: [0,9) classify; 9 zero; 10 tab/svec; [11,45) eaprep;
//       [45,177) gprep x4; [177,249) transposes x4.
__global__ __launch_bounds__(256) void megaprep_kernel(
    const float* W1, const float* W2, const float* We1,
    const float* init_table, const float* s_vec,
    const float* b1, const float* be1, const float* we2,
    const int* ridx, const int* par,
    unsigned short* W2T, unsigned short* We1T,
    unsigned short* tab, unsigned short* svec,
    float* G, float* EA2, float* EWB,
    int* fastlist, int* slowlist, int* cfg, unsigned int* pzero) {
  __shared__ float smem[1056];
  __shared__ int lcnt;
  int job = blockIdx.x;
  int tid = threadIdx.x;

  if (job < 9) {                         // -------- classify (ballot-compaction) ----
    int* out; int cap;
    if (job < 8) { out = fastlist + job * FCAP_; cap = FCAP_; }
    else         { out = slowlist;               cap = SCAP_; }
    if (tid == 0) lcnt = 0;
    __syncthreads();
    int lane = tid & 63;
    unsigned long long lmask_lt = (1ull << lane) - 1ull;
    for (int g = tid; g < ND_; g += 256) {
      int p0 = par[2 * g], p1 = par[2 * g + 1];
      bool fast = (p0 < NI_) && (p1 < NI_);
      bool match = (job < 8) ? (fast && ridx[g] == job) : (!fast);
      unsigned long long mask = __ballot(match);
      if (mask) {
        int leader = __ffsll((unsigned long long)mask) - 1;
        int pre = __popcll(mask & lmask_lt);
        int base_ = 0;
        if (lane == leader) base_ = atomicAdd(&lcnt, __popcll(mask));
        base_ = __shfl(base_, leader, 64);
        if (match) {
          int idx = base_ + pre;
          if (idx < cap) out[idx] = g;
        }
      }
    }
    __syncthreads();
    if (tid == 0) {
      int c = lcnt; if (c > cap) c = cap;
      cfg[job] = c;
    }
  } else if (job == 9) {                 // -------- zero partials (71680 B) --------
    for (int i = tid; i < 17920; i += 256) pzero[i] = 0u;
  } else if (job == 10) {                // -------- tab/svec convert --------
    for (int i = tid; i < 8448; i += 256) {
      if (i < 8192) tab[i] = f2bu(init_table[i]);
      else svec[i - 8192] = f2bu(s_vec[i - 8192]);
    }
  } else if (job < 45) {                 // -------- eaprep: eval-init tables --------
    int q = job - 11;
    int m = q / 17, t = (q % 17) * 2 + (tid >> 7);
    int e = tid & 127;
    if (t <= 32) {
      const float* vec = (t < 32) ? &init_table[(size_t)(m * T_ + t) * D_]
                                  : &s_vec[(size_t)m * D_];
      const float* w = &We1[(size_t)m * D_ * D_];
      float acc = 0.f;
#pragma unroll 8
      for (int d = 0; d < 128; ++d) acc = fmaf(vec[d], w[d * D_ + e], acc);
      if (t < 32) {
        EA2[m * 4096 + ((e >> 1) * 32 + t) * 2 + (e & 1)] = acc + be1[m * D_ + e];
      } else {
        EWB[(m * D_ + e) * 2 + 0] = acc;
        EWB[(m * D_ + e) * 2 + 1] = we2[m * D_ + e];
      }
    }
  } else if (job < 177) {                // -------- gprep x4: G[m][r][slot][t][e] ----
    int q4 = job - 45;
    for (int k = 0; k < 4; ++k) {
      int q = q4 * 4 + k;                // 0..527
      int t = q / 16, mr = q & 15;       // t in [0,32], 32 == svec row
      int m = mr >> 3;
      int slot = tid >> 7, e = tid & 127;
      const float* vec = (t < 32) ? &init_table[(size_t)(m * T_ + t) * D_]
                                  : &s_vec[(size_t)m * D_];
      if (tid < 128) smem[tid] = vec[tid];
      __syncthreads();
      const float* w = &W1[((size_t)mr * 256 + slot * 128) * D_];
      float acc = 0.f;
#pragma unroll 8
      for (int c = 0; c < 128; ++c) acc = fmaf(smem[c], w[c * D_ + e], acc);
      if (slot == 0 && t < 32) acc += b1[mr * D_ + e];
      G[((size_t)(mr * 2 + slot) * 33 + t) * D_ + e] = acc;
      __syncthreads();
    }
  } else {                               // -------- transposes x4 (W2, We1) --------
    int q4 = job - 177;
    for (int k4 = 0; k4 < 4; ++k4) {
      int q0 = q4 * 4 + k4;              // 0..287
      const float* src; unsigned short* dst;
      int rblk, cblk;
      if (q0 < 256) {
        int z = q0 >> 4;
        src = W2 + (size_t)z * 16384; dst = W2T + (size_t)z * 16384;
        rblk = (q0 & 15) >> 2; cblk = q0 & 3;
      } else {
        int q = q0 - 256; int z = q >> 4;
        src = We1 + (size_t)z * 16384; dst = We1T + (size_t)z * 16384;
        rblk = (q & 15) >> 2; cblk = q & 3;
      }
      int r0 = rblk * 32, c0 = cblk * 32;
      float (*tile)[33] = (float(*)[33])smem;
      int tx = tid & 31, ty = tid >> 5;
#pragma unroll
      for (int k = 0; k < 4; ++k)
        tile[ty + 8 * k][tx] = src[(size_t)(r0 + ty + 8 * k) * D_ + c0 + tx];
      __syncthreads();
#pragma unroll
      for (int k = 0; k < 4; ++k)
        dst[(size_t)(c0 + ty + 8 * k) * D_ + r0 + tx] = f2bu(tile[tx][ty + 8 * k]);
      __syncthreads();
    }
  }
}

// ================= main (batched: 642 blocks) =================
// bid<256: fast (m,r,g) loops tiles. bid<512: eval-init x4 chunks.
// bid<514: posneg. bid<642: slow waves (grid-stride 2 rows/wave).
__global__ __launch_bounds__(256) void main_kernel(
    const int* thax, const float* sine, const int* par, const int* ridx,
    const float* pos, const float* neg,
    const float* W1, const float* b1, const float* b2, const float* tweaks,
    const float* G, const unsigned short* W2T, const unsigned short* We1T,
    const unsigned short* tab, const unsigned short* svec,
    const float* EA2, const float* EWB,
    const float* be1, const float* we2, const float* be2,
    const int* cfg, const int* fastlist, const int* slowlist,
    float* pA, float* pB, float* pPok, float* pNok, float* pTp, float* pTn) {
  __shared__ float sbuf[4 * WSL_];       // 4704 floats = 18816 B -> 8 blocks/CU
  int bid = blockIdx.x;
  int tid = threadIdx.x;
  int w = tid >> 6, lane = tid & 63;

  if (bid < 256) {                        // ---------- fast rows (loop tiles) -------
    int m = bid >> 7, r = (bid >> 4) & 7, g = bid & 15;
    int cnt = cfg[r];
    unsigned short* h_lds = (unsigned short*)sbuf;       // [16][128] bf16
    int*   t0a  = (int*)(sbuf + 1024);
    int*   t1a  = t0a + 16;
    float* s0a  = (float*)(t1a + 16);
    float* s1a  = s0a + 16;
    int*   gida = (int*)(s1a + 16);
    float* red2 = sbuf + 1104;                           // [4][16]
    float tw1 = tweaks[m * 2 + 1];
    const float* b2v = &b2[(m * R_ + r) * D_];
    const float* Gm = &G[(size_t)(m * R_ + r) * 8448];
    const unsigned short* w2b = &W2T[(size_t)(m * R_ + r) * D_ * D_];
    const unsigned short* we1b = &We1T[(size_t)m * D_ * D_];
    int l15 = lane & 15, l4 = lane >> 4;

    for (int tile = g; tile * 16 < cnt; tile += 16) {
      int base = tile * 16;
      if (tid < 16) {
        int loc = base + tid; if (loc >= cnt) loc = cnt - 1;
        int gid = fastlist[r * FCAP_ + loc];
        int p0 = par[2 * gid], p1 = par[2 * gid + 1];
        t0a[tid] = thax[p0]; s0a[tid] = sine[p0];
        t1a[tid] = thax[p1]; s1a[tid] = sine[p1];
        gida[tid] = gid;
      }
      __syncthreads();
      {                                   // coop-build h (1 thread = row x 8 dims)
        int row = tid >> 4, seg = tid & 15, d0 = seg * 8;
        int t0 = t0a[row], t1 = t1a[row];
        float s0 = s0a[row], s1 = s1a[row];
        const float* pa = &Gm[t0 * 128 + d0];
        const float* pb = &Gm[(33 + t1) * 128 + d0];
        const float* pu = &Gm[4096 + d0];
        const float* pv = &Gm[8320 + d0];
        bf16x8 hv;
#pragma unroll
        for (int half = 0; half < 2; ++half) {
          float4 a = *(const float4*)(pa + half * 4);
          float4 b = *(const float4*)(pb + half * 4);
          float4 u = *(const float4*)(pu + half * 4);
          float4 v = *(const float4*)(pv + half * 4);
          hv[half * 4 + 0] = (__bf16)fmaxf(a.x + b.x + s0 * u.x + s1 * v.x, 0.f);
          hv[half * 4 + 1] = (__bf16)fmaxf(a.y + b.y + s0 * u.y + s1 * v.y, 0.f);
          hv[half * 4 + 2] = (__bf16)fmaxf(a.z + b.z + s0 * u.z + s1 * v.z, 0.f);
          hv[half * 4 + 3] = (__bf16)fmaxf(a.w + b.w + s0 * u.w + s1 * v.w, 0.f);
        }
        *(bf16x8*)&h_lds[row * 128 + (d0 ^ ((row & 7) << 3))] = hv;
      }
      __syncthreads();
      f32x4 acc[2];
      acc[0] = (f32x4){0.f, 0.f, 0.f, 0.f};
      acc[1] = (f32x4){0.f, 0.f, 0.f, 0.f};
#pragma unroll
      for (int kc = 0; kc < 4; ++kc) {
        int d0 = kc * 32 + l4 * 8;
        bf16x8 a2 = ldb8(&h_lds[l15 * 128 + (d0 ^ ((l15 & 7) << 3))]);
#pragma unroll
        for (int f = 0; f < 2; ++f) {
          int fg = w * 2 + f;
          bf16x8 b = ldb8(&w2b[(fg * 16 + l15) * D_ + d0]);
          acc[f] = __builtin_amdgcn_mfma_f32_16x16x32_bf16(a2, b, acc[f], 0, 0, 0);
        }
      }
      __syncthreads();                    // done reading h_lds (GEMM2)
#pragma unroll
      for (int i = 0; i < 4; ++i) {
        int row = l4 * 4 + i;
#pragma unroll
        for (int f = 0; f < 2; ++f) {
          int e = (w * 2 + f) * 16 + l15;
          h_lds[row * 128 + (e ^ ((row & 7) << 3))] = f2bu(acc[f][i] + b2v[e] + tw1);
        }
      }
      __syncthreads();
      // fused eval: out @ We1 -> relu -> we2
      f32x4 ae[2];
      ae[0] = (f32x4){0.f, 0.f, 0.f, 0.f};
      ae[1] = (f32x4){0.f, 0.f, 0.f, 0.f};
#pragma unroll
      for (int kc = 0; kc < 4; ++kc) {
        int d0 = kc * 32 + l4 * 8;
        bf16x8 a2 = ldb8(&h_lds[l15 * 128 + (d0 ^ ((l15 & 7) << 3))]);
#pragma unroll
        for (int f = 0; f < 2; ++f) {
          int fg = w * 2 + f;
          bf16x8 b = ldb8(&we1b[(fg * 16 + l15) * D_ + d0]);
          ae[f] = __builtin_amdgcn_mfma_f32_16x16x32_bf16(a2, b, ae[f], 0, 0, 0);
        }
      }
      float part[4] = {0.f, 0.f, 0.f, 0.f};
#pragma unroll
      for (int f = 0; f < 2; ++f) {
        int e = (w * 2 + f) * 16 + l15;
        float bb = be1[m * D_ + e];
        float wv = we2[m * D_ + e];
#pragma unroll
        for (int i = 0; i < 4; ++i) {
          float he = ae[f][i] + bb;
          he = he > 0.f ? he : 0.f;
          part[i] += he * wv;
        }
      }
#pragma unroll
      for (int mask = 1; mask < 16; mask <<= 1) {
#pragma unroll
        for (int i = 0; i < 4; ++i) part[i] += __shfl_xor(part[i], mask, 64);
      }
      if (l15 == 0) {
#pragma unroll
        for (int i = 0; i < 4; ++i) red2[w * 16 + l4 * 4 + i] = part[i];
      }
      __syncthreads();
      if (tid < 16) {
        int gg = base + tid;
        float v6[4] = {0.f, 0.f, 0.f, 0.f};
        if (gg < cnt) {
          float logit = red2[tid] + red2[16 + tid] + red2[32 + tid] + red2[48 + tid]
                      + be2[m] + tweaks[m * 2 + 0];
          int grow = NI_ + gida[tid];
          float p_ = pos[grow], n_ = neg[grow];
          float lse = log1pf(__expf(-fabsf(logit)));
          v6[0] = p_ * (fmaxf(-logit, 0.f) + lse);
          v6[1] = n_ * (fmaxf(logit, 0.f) + lse);
          v6[2] = logit >= 0.f ? p_ : 0.f;
          v6[3] = logit < 0.f ? n_ : 0.f;
        }
#pragma unroll
        for (int mask = 1; mask < 16; mask <<= 1) {
#pragma unroll
          for (int qq = 0; qq < 4; ++qq) v6[qq] += __shfl_xor(v6[qq], mask, 64);
        }
        if (tid == 0) {
          int slot = 512 + r * 80 + tile;
          pA[m * PSTRIDE_ + slot] = v6[0];
          pB[m * PSTRIDE_ + slot] = v6[1];
          pPok[m * PSTRIDE_ + slot] = v6[2];
          pNok[m * PSTRIDE_ + slot] = v6[3];
        }
      }
      __syncthreads();                    // LDS reuse next tile
    }
  } else if (bid < 512) {                 // ---------- eval-init (x4 chunks) --------
    int q = bid - 256;
    int m = q >> 7, i0 = q & 127;
    float* lea = sbuf;                    // [p=64][t=32][2]
    float* lwb = sbuf + 4096;             // [e=128][{EB,we2}]
    float* red = sbuf + 4352;
    for (int i = tid; i < 4096; i += 256) lea[i] = EA2[m * 4096 + i];
    if (tid < 256) lwb[tid] = EWB[m * 256 + tid];
    __syncthreads();
    float bev = be2[m], tw0 = tweaks[m * 2 + 0];
    float v[6] = {0.f, 0.f, 0.f, 0.f, 0.f, 0.f};
#pragma unroll
    for (int sub = 0; sub < 4; ++sub) {
      int row = (i0 * 4 + sub) * 256 + tid;
      int t = thax[row];
      float s = sine[row];
      float acc = 0.f;
#pragma unroll 8
      for (int p = 0; p < 64; ++p) {
        float2 ea = *(const float2*)&lea[(p * 32 + t) * 2];
        float4 wb = *(const float4*)&lwb[p * 4];
        float x0 = fmaf(s, wb.x, ea.x); x0 = fmaxf(x0, 0.f);
        acc = fmaf(x0, wb.y, acc);
        float x1 = fmaf(s, wb.z, ea.y); x1 = fmaxf(x1, 0.f);
        acc = fmaf(x1, wb.w, acc);
      }
      float logit = acc + bev + tw0;
      float p_ = pos[row], n_ = neg[row];
      float lse = log1pf(__expf(-fabsf(logit)));
      v[0] += p_ * (fmaxf(-logit, 0.f) + lse);
      v[1] += n_ * (fmaxf(logit, 0.f) + lse);
      if (logit >= 0.f) v[2] += p_; else v[3] += n_;
      v[4] += p_; v[5] += n_;
    }
#pragma unroll
    for (int mask = 1; mask < 64; mask <<= 1) {
#pragma unroll
      for (int k = 0; k < 6; ++k) v[k] += __shfl_xor(v[k], mask, 64);
    }
    if (lane == 0) {
#pragma unroll
      for (int k = 0; k < 6; ++k) red[k * 16 + w] = v[k];
    }
    __syncthreads();
    if (tid == 0) {
      float t6[6];
#pragma unroll
      for (int k = 0; k < 6; ++k)
        t6[k] = red[k * 16 + 0] + red[k * 16 + 1] + red[k * 16 + 2] + red[k * 16 + 3];
      pA[m * PSTRIDE_ + i0] = t6[0];
      pB[m * PSTRIDE_ + i0] = t6[1];
      pPok[m * PSTRIDE_ + i0] = t6[2];
      pNok[m * PSTRIDE_ + i0] = t6[3];
      if (m == 0) { pTp[i0] = t6[4]; pTn[i0] = t6[5]; }
    }
  } else if (bid < 514) {                 // ---------- deriv pos/neg total ----------
    int j = bid - 512;                    // 0: pos, 1: neg
    float* red = sbuf;
    const float* src = j ? neg : pos;
    float s = 0.f;
    for (int i = NI_ + tid; i < N_; i += 256) s += src[i];
#pragma unroll
    for (int mask = 1; mask < 64; mask <<= 1) s += __shfl_xor(s, mask, 64);
    if (lane == 0) red[w] = s;
    __syncthreads();
    if (tid == 0) {
      float t = red[0] + red[1] + red[2] + red[3];
      if (j == 0) pTp[1152] = t; else pTn[1152] = t;
    }
  } else {                                // ---------- slow rows: WAVE each, x2 -----
    int wbase = (bid - 514) * 4 + w;      // 0..511
    int*   ilist = (int*)&sbuf[w * WSL_];                   // [17] (+nn at [16])
    float* hbuf  = &sbuf[w * WSL_ + 18];                    // [128] f32
    unsigned short* cacheu = (unsigned short*)&sbuf[w * WSL_ + 146]; // [16][128] bf16
    unsigned short* cathi  = (unsigned short*)hbuf;         // overlay (cat hi half)

    for (int s = wbase; s < 1024; s += 512) {
      int m = s >> 9, si = s & 511;
      if (si >= cfg[8]) continue;
      int g_row = slowlist[si];
      if (lane == 0) {
        int nn = 0;
        ilist[nn++] = g_row;
        for (int i = 0; i < nn; ++i) {            // BFS closure over deriv ancestors
          int g = ilist[i];
          for (int ss = 0; ss < 2; ++ss) {
            int p = par[2 * g + ss];
            if (p >= NI_) {
              int pg = p - NI_;
              bool found = false;
              for (int jj = 0; jj < nn; ++jj) if (ilist[jj] == pg) { found = true; break; }
              if (!found && nn < CCAP_) ilist[nn++] = pg;
            }
          }
        }
        for (int i = 1; i < nn; ++i) {            // sort ascending (parents first)
          int v = ilist[i]; int jj = i - 1;
          while (jj >= 0 && ilist[jj] > v) { ilist[jj + 1] = ilist[jj]; --jj; }
          ilist[jj + 1] = v;
        }
        ilist[16] = nn;
      }
      WAVE_FENCE();
      int NN = ilist[16];
      float tw1v = tweaks[m * 2 + 1];
      for (int j = 0; j < NN; ++j) {
        int g = ilist[j];
        int r = ridx[g];
        int p0 = par[2 * g], p1 = par[2 * g + 1];
        bool fastn = (p0 < NI_) && (p1 < NI_);
        if (fastn) {                              // h via G tables (2 dims/lane)
          const float* Gm = &G[(size_t)(m * R_ + r) * 8448];
          int t0 = thax[p0], t1 = thax[p1];
          float s0 = sine[p0], s1 = sine[p1];
#pragma unroll
          for (int k = 0; k < 2; ++k) {
            int d = lane + k * 64;
            float hv = Gm[t0 * 128 + d] + Gm[(33 + t1) * 128 + d]
                     + s0 * Gm[4096 + d] + s1 * Gm[8320 + d];
            hbuf[d] = bfu2f(f2bu(fmaxf(hv, 0.f)));
          }
        } else {                                  // GEMM1 over cat (cat overlaid)
          unsigned short* catlo = &cacheu[j * 128];   // slot j free until GEMM2
          int s0s = -1, s1s = -1;
          if (p0 >= NI_) for (int jj = 0; jj < j; ++jj) if (ilist[jj] == p0 - NI_) { s0s = jj; break; }
          if (p1 >= NI_) for (int jj = 0; jj < j; ++jj) if (ilist[jj] == p1 - NI_) { s1s = jj; break; }
#pragma unroll
          for (int k = 0; k < 4; ++k) {           // build cat (4 entries/lane)
            int c = lane * 4 + k;
            int p = (c < 128) ? p0 : p1; int cc = c & 127;
            int slot = (c < 128) ? s0s : s1s;
            unsigned short v;
            if (p < NI_) {
              v = f2bu(bfu2f(tab[(m * T_ + thax[p]) * D_ + cc])
                       + sine[p] * bfu2f(svec[m * D_ + cc]));
            } else {
              v = cacheu[slot * 128 + cc];
            }
            if (c < 128) catlo[c] = v; else cathi[c - 128] = v;
          }
          WAVE_FENCE();
          int d0 = lane, d1 = lane + 64;
          const float* w1r = &W1[((size_t)(m * R_ + r)) * 256 * D_];
          float a0 = b1[(m * R_ + r) * D_ + d0];
          float a1 = b1[(m * R_ + r) * D_ + d1];
          for (int c = 0; c < 256; ++c) {
            float cv = bfu2f(c < 128 ? catlo[c] : cathi[c - 128]);
            a0 = fmaf(cv, w1r[(size_t)c * D_ + d0], a0);
            a1 = fmaf(cv, w1r[(size_t)c * D_ + d1], a1);
          }
          WAVE_FENCE();                           // all lanes done reading cat
          hbuf[d0] = bfu2f(f2bu(fmaxf(a0, 0.f))); // overwrites cathi (safe now)
          hbuf[d1] = bfu2f(f2bu(fmaxf(a1, 0.f)));
        }
        WAVE_FENCE();
        // GEMM2 -> cache[j] (2 e-dims/lane, dual acc)
        int e0 = lane, e1 = lane + 64;
        const unsigned short* w2r0 = &W2T[((size_t)(m * R_ + r) * D_ + e0) * D_];
        const unsigned short* w2r1 = &W2T[((size_t)(m * R_ + r) * D_ + e1) * D_];
        float ac0 = 0.f, ac1 = 0.f;
        for (int d = 0; d < 128; ++d) {
          float hv = hbuf[d];
          ac0 = fmaf(bfu2f(w2r0[d]), hv, ac0);
          ac1 = fmaf(bfu2f(w2r1[d]), hv, ac1);
        }
        WAVE_FENCE();                             // all lanes done reading hbuf
        cacheu[j * 128 + e0] = f2bu(ac0 + b2[(m * R_ + r) * D_ + e0] + tw1v);
        cacheu[j * 128 + e1] = f2bu(ac1 + b2[(m * R_ + r) * D_ + e1] + tw1v);
        WAVE_FENCE();
      }
      // fused eval of the row (largest index -> last after sort)
      int jr = NN - 1;
      float part = 0.f;
#pragma unroll
      for (int k = 0; k < 2; ++k) {
        int e = lane + k * 64;
        const unsigned short* wer = &We1T[((size_t)m * D_ + e) * D_];
        float acc = 0.f;
        for (int d = 0; d < 128; ++d)
          acc = fmaf(bfu2f(wer[d]), bfu2f(cacheu[jr * 128 + d]), acc);
        float he = acc + be1[m * D_ + e];
        he = he > 0.f ? he : 0.f;
        part += he * we2[m * D_ + e];
      }
#pragma unroll
      for (int mask = 1; mask < 64; mask <<= 1) part += __shfl_xor(part, mask, 64);
      if (lane == 0) {
        float logit = part + be2[m] + tweaks[m * 2 + 0];
        int grow = NI_ + g_row;
        float p_ = pos[grow], n_ = neg[grow];
        float lse = log1pf(__expf(-fabsf(logit)));
        int slot = 1153 + si;
        pA[m * PSTRIDE_ + slot] = p_ * (fmaxf(-logit, 0.f) + lse);
        pB[m * PSTRIDE_ + slot] = n_ * (fmaxf(logit, 0.f) + lse);
        pPok[m * PSTRIDE_ + slot] = logit >= 0.f ? p_ : 0.f;
        pNok[m * PSTRIDE_ + slot] = logit < 0.f ? n_ : 0.f;
      }
      WAVE_FENCE();
    }
  }
}

// ---------------- deterministic final reduction ----------------
__global__ __launch_bounds__(256) void finalize_kernel(
    const float* pA, const float* pB, const float* pPok, const float* pNok,
    const float* pTp, const float* pTn, float* out) {
  __shared__ float lred[10][4];
  const float* srcs[10] = {pA, pA + PSTRIDE_, pB, pB + PSTRIDE_,
                           pPok, pPok + PSTRIDE_, pNok, pNok + PSTRIDE_,
                           pTp, pTn};
  int tid = threadIdx.x;
  int w = tid >> 6, lane = tid & 63;
#pragma unroll
  for (int q = 0; q < 10; ++q) {
    float s = 0.f;
    for (int i = tid; i < PUSED_; i += 256) s += srcs[q][i];
#pragma unroll
    for (int mask = 1; mask < 64; mask <<= 1) s += __shfl_xor(s, mask, 64);
    if (lane == 0) lred[q][w] = s;
  }
  __syncthreads();
  if (tid == 0) {
    float totals[10];
#pragma unroll
    for (int q = 0; q < 10; ++q)
      totals[q] = lred[q][0] + lred[q][1] + lred[q][2] + lred[q][3];
    float tp = totals[8], tn = totals[9];
    float pw = tn / tp;
    out[0] = pw * totals[0] + totals[2];
    out[1] = pw * totals[1] + totals[3];
    out[2] = totals[4]; out[3] = totals[5];
    out[4] = totals[6]; out[5] = totals[7];
    out[6] = tp; out[7] = tn;
  }
}

extern "C" void kernel_launch(void* const* d_in, const int* in_sizes, int n_in,
                              void* d_out, int out_size, void* d_ws, size_t ws_size,
                              hipStream_t stream) {
  const int*   thax = (const int*)d_in[0];
  const float* sine = (const float*)d_in[1];
  const int*   par  = (const int*)d_in[2];
  const int*   ridx = (const int*)d_in[3];
  const float* pos  = (const float*)d_in[4];
  const float* neg  = (const float*)d_in[5];
  const float* init_table = (const float*)d_in[6];
  const float* s_vec = (const float*)d_in[7];
  const float* W1 = (const float*)d_in[8];
  const float* b1 = (const float*)d_in[9];
  const float* W2 = (const float*)d_in[10];
  const float* b2 = (const float*)d_in[11];
  const float* tweaks = (const float*)d_in[12];
  const float* We1 = (const float*)d_in[13];
  const float* be1 = (const float*)d_in[14];
  const float* we2 = (const float*)d_in[15];
  const float* be2 = (const float*)d_in[16];

  char* ws = (char*)d_ws;
  unsigned short* W2T  = (unsigned short*)(ws + OFF_W2T);
  unsigned short* We1T = (unsigned short*)(ws + OFF_WE1T);
  unsigned short* tab  = (unsigned short*)(ws + OFF_TAB);
  unsigned short* svec = (unsigned short*)(ws + OFF_SVEC);
  float* EA2  = (float*)(ws + OFF_EA2);
  float* EWB  = (float*)(ws + OFF_EWB);
  float* pA   = (float*)(ws + OFF_PA);
  float* pB   = (float*)(ws + OFF_PB);
  float* pPok = (float*)(ws + OFF_PPOK);
  float* pNok = (float*)(ws + OFF_PNOK);
  float* pTp  = (float*)(ws + OFF_PTP);
  float* pTn  = (float*)(ws + OFF_PTN);
  float* G    = (float*)(ws + OFF_G);
  int* fastlist = (int*)(ws + OFF_FLIST);
  int* slowlist = (int*)(ws + OFF_SLIST);
  int* cfg      = (int*)(ws + OFF_CFG);

  megaprep_kernel<<<249, 256, 0, stream>>>(
      W1, W2, We1, init_table, s_vec, b1, be1, we2, ridx, par,
      W2T, We1T, tab, svec, G, EA2, EWB,
      fastlist, slowlist, cfg, (unsigned int*)pA);
  main_kernel<<<642, 256, 0, stream>>>(
      thax, sine, par, ridx, pos, neg, W1, b1, b2, tweaks,
      G, W2T, We1T, tab, svec, EA2, EWB, be1, we2, be2,
      cfg, fastlist, slowlist,
      pA, pB, pPok, pNok, pTp, pTn);
  finalize_kernel<<<1, 256, 0, stream>>>(pA, pB, pPok, pNok, pTp, pTn,
                                         (float*)d_out);
}

// Round 21
// 88.484 us; speedup vs baseline: 1.4005x; 1.4005x over previous
//
#include <hip/hip_runtime.h>
#include <hip/hip_bf16.h>

#define M_ 2
#define D_ 128
#define NI_ 131072
#define L_ 4
#define NPL_ 2048
#define R_ 8
#define T_ 32
#define N_ (NI_ + L_ * NPL_)   // 139264
#define ND_ (L_ * NPL_)        // 8192 deriv nodes
#define PSTRIDE_ 1792          // per-model partial stride (floats)
#define PUSED_ 1665            // 512 init + 640 fast + 1 posneg + 512 slow
#define FCAP_ 1280             // fast rows capacity per rule (exp ~979)
#define SCAP_ 512              // slow rows capacity total    (exp ~368)
#define CCAP_ 24               // ancestor-closure cap per slow row (max possible 15)

typedef __bf16 bf16x8 __attribute__((ext_vector_type(8)));
typedef float f32x4 __attribute__((ext_vector_type(4)));
typedef unsigned short u16x4 __attribute__((ext_vector_type(4)));

// ---- ws layout (bytes) ----
#define OFF_W2T    0u            // [M][R][128(e)][128(d)] bf16 = 524288
#define OFF_WE1T   524288u       // [M][128(e)][128(d)] bf16    = 65536
#define OFF_TAB    589824u       // [M][T][128] bf16            = 16384
#define OFF_SVEC   606208u       // [M][128] bf16               = 512
#define OFF_EA2    606720u       // [M][64][32][2] f32          = 32768
#define OFF_EWB    639488u       // [M][128][2] f32             = 2048
#define OFF_PA     641536u       // [2][1792] f32 (pA..pTn contiguous 71680 B)
#define OFF_PB     655872u
#define OFF_PPOK   670208u
#define OFF_PNOK   684544u
#define OFF_PTP    698880u       // [1792] f32
#define OFF_PTN    706048u       // end 713216
#define OFF_G      713216u       // [M][R][2][33][128] f32 = 540672 (b1 folded slot-a t<32)
#define OFF_FLIST  1253888u      // [8][1280] int = 40960
#define OFF_SLIST  1294848u      // [512] int = 2048
#define OFF_CFG    1296896u      // [12] int (0..7 fast counts, 8 slow count)

__device__ __forceinline__ unsigned short f2bu(float f) {
  unsigned int u = __float_as_uint(f);
  u += 0x7fffu + ((u >> 16) & 1u);        // RNE (finite values only)
  return (unsigned short)(u >> 16);
}
__device__ __forceinline__ float bfu2f(unsigned short u) {
  return __uint_as_float((unsigned int)u << 16);
}
__device__ __forceinline__ bf16x8 ldb8(const unsigned short* p) {
  return *reinterpret_cast<const bf16x8*>(p);
}

// ================= mega-prep (333 blocks) =================
// jobs: [0,9) classify; [9,41) gprep-GEMM (mr,slot); [41,43) eaprep-GEMM (m);
//       43 zero partials; 44 tab/svec; [45,333) transposes (W2,We1).
__global__ __launch_bounds__(256) void megaprep_kernel(
    const float* W1, const float* W2, const float* We1,
    const float* init_table, const float* s_vec,
    const float* b1, const float* be1, const float* we2,
    const int* ridx, const int* par,
    unsigned short* W2T, unsigned short* We1T,
    unsigned short* tab, unsigned short* svec,
    float* G, float* EA2, float* EWB,
    int* fastlist, int* slowlist, int* cfg, unsigned int* pzero) {
  __shared__ float smem[4352];           // vtab [34][128] (row 33 zero) / transpose tile
  __shared__ int lcnt;
  int job = blockIdx.x;
  int tid = threadIdx.x;

  if (job < 9) {                         // -------- classify (ballot-compaction) ----
    int* out; int cap;
    if (job < 8) { out = fastlist + job * FCAP_; cap = FCAP_; }
    else         { out = slowlist;               cap = SCAP_; }
    if (tid == 0) lcnt = 0;
    __syncthreads();
    int lane = tid & 63;
    unsigned long long lmask_lt = (1ull << lane) - 1ull;
    for (int g = tid; g < ND_; g += 256) {
      int p0 = par[2 * g], p1 = par[2 * g + 1];
      bool fast = (p0 < NI_) && (p1 < NI_);
      bool match = (job < 8) ? (fast && ridx[g] == job) : (!fast);
      unsigned long long mask = __ballot(match);
      if (mask) {
        int leader = __ffsll((unsigned long long)mask) - 1;
        int pre = __popcll(mask & lmask_lt);
        int base_ = 0;
        if (lane == leader) base_ = atomicAdd(&lcnt, __popcll(mask));
        base_ = __shfl(base_, leader, 64);
        if (match) {
          int idx = base_ + pre;
          if (idx < cap) out[idx] = g;
        }
      }
    }
    __syncthreads();
    if (tid == 0) {
      int c = lcnt; if (c > cap) c = cap;
      cfg[job] = c;
    }
  } else if (job < 41) {                 // -------- gprep-GEMM: one block per (mr,slot)
    int q = job - 9;
    int mr = q >> 1, slot = q & 1;
    int m = mr >> 3;
    for (int i = tid; i < 4352; i += 256) {
      int t = i >> 7, c = i & 127;
      smem[i] = (t < 32) ? init_table[(size_t)(m * T_ + t) * D_ + c]
              : (t == 32) ? s_vec[(size_t)m * D_ + c] : 0.f;
    }
    __syncthreads();
    int e = tid & 127, tg = tid >> 7;
    int t0 = tg ? 17 : 0;
    int nt = tg ? 16 : 17;
    float acc[17];
#pragma unroll
    for (int k = 0; k < 17; ++k) acc[k] = 0.f;
    const float* w1base = &W1[(size_t)(mr * 256 + slot * 128) * D_ + e];
#pragma unroll 4
    for (int c = 0; c < 128; ++c) {
      float w1c = w1base[(size_t)c * D_];
#pragma unroll
      for (int k = 0; k < 17; ++k)
        acc[k] = fmaf(smem[(t0 + k) * 128 + c], w1c, acc[k]);
    }
    float bb = b1[mr * D_ + e];
    for (int k = 0; k < nt; ++k) {
      int t = t0 + k;
      float v = acc[k];
      if (slot == 0 && t < 32) v += bb;        // fold b1 into slot-a rows
      G[((size_t)(mr * 2 + slot) * 33 + t) * D_ + e] = v;
    }
  } else if (job < 43) {                 // -------- eaprep-GEMM: one block per m ----
    int m = job - 41;
    for (int i = tid; i < 4352; i += 256) {
      int t = i >> 7, c = i & 127;
      smem[i] = (t < 32) ? init_table[(size_t)(m * T_ + t) * D_ + c]
              : (t == 32) ? s_vec[(size_t)m * D_ + c] : 0.f;
    }
    __syncthreads();
    int e = tid & 127, tg = tid >> 7;
    int t0 = tg ? 17 : 0;
    int nt = tg ? 16 : 17;
    float acc[17];
#pragma unroll
    for (int k = 0; k < 17; ++k) acc[k] = 0.f;
    const float* webase = &We1[(size_t)m * D_ * D_ + e];
#pragma unroll 4
    for (int c = 0; c < 128; ++c) {
      float wc = webase[(size_t)c * D_];
#pragma unroll
      for (int k = 0; k < 17; ++k)
        acc[k] = fmaf(smem[(t0 + k) * 128 + c], wc, acc[k]);
    }
    float bev = be1[m * D_ + e];
    for (int k = 0; k < nt; ++k) {
      int t = t0 + k;
      if (t < 32) {
        EA2[m * 4096 + ((e >> 1) * 32 + t) * 2 + (e & 1)] = acc[k] + bev;
      } else {
        EWB[(m * D_ + e) * 2 + 0] = acc[k];
        EWB[(m * D_ + e) * 2 + 1] = we2[m * D_ + e];
      }
    }
  } else if (job == 43) {                // -------- zero partials (71680 B) --------
    for (int i = tid; i < 17920; i += 256) pzero[i] = 0u;
  } else if (job == 44) {                // -------- tab/svec convert --------
    for (int i = tid; i < 8448; i += 256) {
      if (i < 8192) tab[i] = f2bu(init_table[i]);
      else svec[i - 8192] = f2bu(s_vec[i - 8192]);
    }
  } else {                               // -------- transposes (W2: 256, We1: 32) ----
    int q0 = job - 45;
    const float* src; unsigned short* dst;
    int rblk, cblk;
    if (q0 < 256) {
      int z = q0 >> 4;
      src = W2 + (size_t)z * 16384; dst = W2T + (size_t)z * 16384;
      rblk = (q0 & 15) >> 2; cblk = q0 & 3;
    } else {
      int q = q0 - 256; int z = q >> 4;
      src = We1 + (size_t)z * 16384; dst = We1T + (size_t)z * 16384;
      rblk = (q & 15) >> 2; cblk = q & 3;
    }
    int r0 = rblk * 32, c0 = cblk * 32;
    float (*tile)[33] = (float(*)[33])smem;
    int tx = tid & 31, ty = tid >> 5;
#pragma unroll
    for (int k = 0; k < 4; ++k)
      tile[ty + 8 * k][tx] = src[(size_t)(r0 + ty + 8 * k) * D_ + c0 + tx];
    __syncthreads();
#pragma unroll
    for (int k = 0; k < 4; ++k)
      dst[(size_t)(c0 + ty + 8 * k) * D_ + r0 + tx] = f2bu(tile[tx][ty + 8 * k]);
  }
}

// ================= main: slow FIRST, then fast, eval-init, posneg ===============
// grid 3330. bid<1024: slow closure row (dispatched first -> overlaps).
// bid<2304: fast tile. bid<3328: eval-init. bid<3330: posneg.
__global__ __launch_bounds__(256) void main_kernel(
    const int* thax, const float* sine, const int* par, const int* ridx,
    const float* pos, const float* neg,
    const float* W1, const float* b1, const float* b2, const float* tweaks,
    const float* G, const unsigned short* W2T, const unsigned short* We1T,
    const unsigned short* tab, const unsigned short* svec,
    const float* EA2, const float* EWB,
    const float* be1, const float* we2, const float* be2,
    const int* cfg, const int* fastlist, const int* slowlist,
    float* pA, float* pB, float* pPok, float* pNok, float* pTp, float* pTn) {
  __shared__ float sbuf[4448];
  int bid = blockIdx.x;
  int tid = threadIdx.x;
  int w = tid >> 6, lane = tid & 63;

  if (bid < 1024) {                       // ---------- slow row: analytic closure ----
    int m = bid >> 9, si = bid & 511;
    if (si >= cfg[8]) return;
    int*   list  = (int*)sbuf;                              // [CCAP_]
    int*   meta  = (int*)(sbuf + 24);                       // nn, slot0, slot1
    unsigned short* catl = (unsigned short*)(sbuf + 32);    // [256] bf16
    float* hbuf  = sbuf + 160;                              // [128]
    float* hp0   = sbuf + 288;                              // [128]
    float* hp1   = sbuf + 416;                              // [128]
    unsigned short* cache = (unsigned short*)(sbuf + 544);  // [CCAP_][128] bf16

    int g_row = slowlist[si];
    if (tid == 0) {
      int nn = 0;
      list[nn++] = g_row;
      for (int i = 0; i < nn; ++i) {              // BFS closure over deriv ancestors
        int g = list[i];
        for (int s = 0; s < 2; ++s) {
          int p = par[2 * g + s];
          if (p >= NI_) {
            int pg = p - NI_;
            bool found = false;
            for (int jj = 0; jj < nn; ++jj) if (list[jj] == pg) { found = true; break; }
            if (!found && nn < CCAP_) list[nn++] = pg;
          }
        }
      }
      for (int i = 1; i < nn; ++i) {              // sort ascending (parents first)
        int v = list[i]; int jj = i - 1;
        while (jj >= 0 && list[jj] > v) { list[jj + 1] = list[jj]; --jj; }
        list[jj + 1] = v;
      }
      meta[0] = nn;
    }
    __syncthreads();
    int NN = meta[0];
    float tw1 = tweaks[m * 2 + 1];
    for (int j = 0; j < NN; ++j) {
      int g = list[j];
      int r = ridx[g];
      int p0 = par[2 * g], p1 = par[2 * g + 1];
      bool fastn = (p0 < NI_) && (p1 < NI_);
      if (fastn) {                                // h via G tables
        if (tid < 128) {
          int d = tid;
          const float* Gm = &G[(size_t)(m * R_ + r) * 8448];
          float hv = Gm[thax[p0] * 128 + d] + Gm[(33 + thax[p1]) * 128 + d]
                   + sine[p0] * Gm[4096 + d] + sine[p1] * Gm[8320 + d];
          hbuf[d] = bfu2f(f2bu(fmaxf(hv, 0.f)));
        }
        __syncthreads();
      } else {                                    // slow node: GEMM1 over cat
        if (tid == 0) {
          int s0 = -1, s1 = -1;
          if (p0 >= NI_) for (int jj = 0; jj < j; ++jj) if (list[jj] == p0 - NI_) { s0 = jj; break; }
          if (p1 >= NI_) for (int jj = 0; jj < j; ++jj) if (list[jj] == p1 - NI_) { s1 = jj; break; }
          meta[1] = s0; meta[2] = s1;
        }
        __syncthreads();
        {
          int c = tid; int p = (c < 128) ? p0 : p1; int cc = c & 127;
          int slot = (c < 128) ? meta[1] : meta[2];
          unsigned short v;
          if (p < NI_) {
            float tv = bfu2f(tab[(m * T_ + thax[p]) * D_ + cc])
                     + sine[p] * bfu2f(svec[m * D_ + cc]);
            v = f2bu(tv);
          } else {
            v = cache[slot * 128 + cc];
          }
          catl[c] = v;
        }
        __syncthreads();
        int d = tid & 127, half = tid >> 7;
        const float* w1r = &W1[(((size_t)(m * R_ + r)) * 256 + half * 128) * D_];
        float acc = 0.f;
#pragma unroll 8
        for (int c = 0; c < 128; ++c)
          acc = fmaf(bfu2f(catl[half * 128 + c]), w1r[(size_t)c * D_ + d], acc);
        if (half == 0) hp0[d] = acc; else hp1[d] = acc;
        __syncthreads();
        if (tid < 128) {
          float hv = b1[(m * R_ + r) * D_ + tid] + hp0[tid] + hp1[tid];
          hbuf[tid] = bfu2f(f2bu(fmaxf(hv, 0.f)));
        }
        __syncthreads();
      }
      // GEMM2 -> cache[j]
      {
        int e = tid & 127, half = tid >> 7;
        const u16x4* w2r4 = (const u16x4*)&W2T[((size_t)(m * R_ + r) * D_ + e) * D_ + half * 64];
        float acc = 0.f;
#pragma unroll
        for (int dd = 0; dd < 16; ++dd) {
          u16x4 wv = w2r4[dd];
          int db = half * 64 + dd * 4;
          acc = fmaf(bfu2f(wv[0]), hbuf[db + 0], acc);
          acc = fmaf(bfu2f(wv[1]), hbuf[db + 1], acc);
          acc = fmaf(bfu2f(wv[2]), hbuf[db + 2], acc);
          acc = fmaf(bfu2f(wv[3]), hbuf[db + 3], acc);
        }
        if (half == 0) hp0[e] = acc; else hp1[e] = acc;
      }
      __syncthreads();
      if (tid < 128) {
        float o = hp0[tid] + hp1[tid] + b2[(m * R_ + r) * D_ + tid] + tw1;
        cache[j * 128 + tid] = f2bu(o);
      }
      __syncthreads();
    }
    // fused eval of the row (largest index -> last after sort)
    int jr = NN - 1;
    {
      int e = tid & 127, half = tid >> 7;
      const u16x4* wer4 = (const u16x4*)&We1T[((size_t)m * D_ + e) * D_ + half * 64];
      float acc = 0.f;
#pragma unroll
      for (int dd = 0; dd < 16; ++dd) {
        u16x4 wv = wer4[dd];
        int db = half * 64 + dd * 4;
        acc = fmaf(bfu2f(wv[0]), bfu2f(cache[jr * 128 + db + 0]), acc);
        acc = fmaf(bfu2f(wv[1]), bfu2f(cache[jr * 128 + db + 1]), acc);
        acc = fmaf(bfu2f(wv[2]), bfu2f(cache[jr * 128 + db + 2]), acc);
        acc = fmaf(bfu2f(wv[3]), bfu2f(cache[jr * 128 + db + 3]), acc);
      }
      if (half == 0) hp0[e] = acc; else hp1[e] = acc;
    }
    __syncthreads();
    if (tid < 128) {
      float he = hp0[tid] + hp1[tid] + be1[m * D_ + tid];
      he = he > 0.f ? he : 0.f;
      hbuf[tid] = he * we2[m * D_ + tid];
    }
    __syncthreads();
    if (tid < 64) {
      float s = hbuf[tid] + hbuf[tid + 64];
#pragma unroll
      for (int mask = 1; mask < 64; mask <<= 1) s += __shfl_xor(s, mask, 64);
      if (tid == 0) {
        float logit = s + be2[m] + tweaks[m * 2 + 0];
        int grow = NI_ + g_row;
        float p_ = pos[grow], n_ = neg[grow];
        float lse = log1pf(__expf(-fabsf(logit)));
        int slot = 1153 + si;
        pA[m * PSTRIDE_ + slot] = p_ * (fmaxf(-logit, 0.f) + lse);
        pB[m * PSTRIDE_ + slot] = n_ * (fmaxf(logit, 0.f) + lse);
        pPok[m * PSTRIDE_ + slot] = logit >= 0.f ? p_ : 0.f;
        pNok[m * PSTRIDE_ + slot] = logit < 0.f ? n_ : 0.f;
      }
    }
  } else if (bid < 2304) {                // ---------- fast rows ----------
    int fb = bid - 1024;
    int m = fb / 640, q = fb % 640;
    int r = q / 80, tile = q % 80;
    int cnt = cfg[r];
    int base = tile * 16;
    if (base >= cnt) return;
    unsigned short* h_lds = (unsigned short*)sbuf;       // [16][128] bf16
    int*   t0a  = (int*)(sbuf + 1024);
    int*   t1a  = t0a + 16;
    float* s0a  = (float*)(t1a + 16);
    float* s1a  = s0a + 16;
    int*   gida = (int*)(s1a + 16);
    float* red2 = sbuf + 1104;                           // [4][16]
    if (tid < 16) {
      int loc = base + tid; if (loc >= cnt) loc = cnt - 1;
      int gid = fastlist[r * FCAP_ + loc];
      int p0 = par[2 * gid], p1 = par[2 * gid + 1];
      t0a[tid] = thax[p0]; s0a[tid] = sine[p0];
      t1a[tid] = thax[p1]; s1a[tid] = sine[p1];
      gida[tid] = gid;
    }
    __syncthreads();
    const float* Gm = &G[(size_t)(m * R_ + r) * 8448];
    {                                     // coop-build h (1 thread = row x 8 dims)
      int row = tid >> 4, seg = tid & 15, d0 = seg * 8;
      int t0 = t0a[row], t1 = t1a[row];
      float s0 = s0a[row], s1 = s1a[row];
      const float* pa = &Gm[t0 * 128 + d0];
      const float* pb = &Gm[(33 + t1) * 128 + d0];
      const float* pu = &Gm[4096 + d0];
      const float* pv = &Gm[8320 + d0];
      bf16x8 hv;
#pragma unroll
      for (int half = 0; half < 2; ++half) {
        float4 a = *(const float4*)(pa + half * 4);
        float4 b = *(const float4*)(pb + half * 4);
        float4 u = *(const float4*)(pu + half * 4);
        float4 v = *(const float4*)(pv + half * 4);
        hv[half * 4 + 0] = (__bf16)fmaxf(a.x + b.x + s0 * u.x + s1 * v.x, 0.f);
        hv[half * 4 + 1] = (__bf16)fmaxf(a.y + b.y + s0 * u.y + s1 * v.y, 0.f);
        hv[half * 4 + 2] = (__bf16)fmaxf(a.z + b.z + s0 * u.z + s1 * v.z, 0.f);
        hv[half * 4 + 3] = (__bf16)fmaxf(a.w + b.w + s0 * u.w + s1 * v.w, 0.f);
      }
      *(bf16x8*)&h_lds[row * 128 + (d0 ^ ((row & 7) << 3))] = hv;
    }
    __syncthreads();
    int l15 = lane & 15, l4 = lane >> 4;  // GEMM2: 4 waves x 2 f each
    const unsigned short* w2b = &W2T[(size_t)(m * R_ + r) * D_ * D_];
    f32x4 acc[2];
    acc[0] = (f32x4){0.f, 0.f, 0.f, 0.f};
    acc[1] = (f32x4){0.f, 0.f, 0.f, 0.f};
#pragma unroll
    for (int kc = 0; kc < 4; ++kc) {
      int d0 = kc * 32 + l4 * 8;
      bf16x8 a2 = ldb8(&h_lds[l15 * 128 + (d0 ^ ((l15 & 7) << 3))]);
#pragma unroll
      for (int f = 0; f < 2; ++f) {
        int fg = w * 2 + f;
        bf16x8 b = ldb8(&w2b[(fg * 16 + l15) * D_ + d0]);
        acc[f] = __builtin_amdgcn_mfma_f32_16x16x32_bf16(a2, b, acc[f], 0, 0, 0);
      }
    }
    float tw1 = tweaks[m * 2 + 1];
    const float* b2v = &b2[(m * R_ + r) * D_];
    __syncthreads();                      // done reading h_lds (GEMM2)
#pragma unroll
    for (int i = 0; i < 4; ++i) {
      int row = l4 * 4 + i;
#pragma unroll
      for (int f = 0; f < 2; ++f) {
        int e = (w * 2 + f) * 16 + l15;
        h_lds[row * 128 + (e ^ ((row & 7) << 3))] = f2bu(acc[f][i] + b2v[e] + tw1);
      }
    }
    __syncthreads();
    // fused eval: out @ We1 -> relu -> we2
    f32x4 ae[2];
    ae[0] = (f32x4){0.f, 0.f, 0.f, 0.f};
    ae[1] = (f32x4){0.f, 0.f, 0.f, 0.f};
    const unsigned short* we1b = &We1T[(size_t)m * D_ * D_];
#pragma unroll
    for (int kc = 0; kc < 4; ++kc) {
      int d0 = kc * 32 + l4 * 8;
      bf16x8 a2 = ldb8(&h_lds[l15 * 128 + (d0 ^ ((l15 & 7) << 3))]);
#pragma unroll
      for (int f = 0; f < 2; ++f) {
        int fg = w * 2 + f;
        bf16x8 b = ldb8(&we1b[(fg * 16 + l15) * D_ + d0]);
        ae[f] = __builtin_amdgcn_mfma_f32_16x16x32_bf16(a2, b, ae[f], 0, 0, 0);
      }
    }
    float part[4] = {0.f, 0.f, 0.f, 0.f};
#pragma unroll
    for (int f = 0; f < 2; ++f) {
      int e = (w * 2 + f) * 16 + l15;
      float bb = be1[m * D_ + e];
      float wv = we2[m * D_ + e];
#pragma unroll
      for (int i = 0; i < 4; ++i) {
        float he = ae[f][i] + bb;
        he = he > 0.f ? he : 0.f;
        part[i] += he * wv;
      }
    }
#pragma unroll
    for (int mask = 1; mask < 16; mask <<= 1) {
#pragma unroll
      for (int i = 0; i < 4; ++i) part[i] += __shfl_xor(part[i], mask, 64);
    }
    if (l15 == 0) {
#pragma unroll
      for (int i = 0; i < 4; ++i) red2[w * 16 + l4 * 4 + i] = part[i];
    }
    __syncthreads();
    if (tid < 16) {
      int g = base + tid;
      float v6[4] = {0.f, 0.f, 0.f, 0.f};
      if (g < cnt) {
        float logit = red2[tid] + red2[16 + tid] + red2[32 + tid] + red2[48 + tid]
                    + be2[m] + tweaks[m * 2 + 0];
        int grow = NI_ + gida[tid];
        float p_ = pos[grow], n_ = neg[grow];
        float lse = log1pf(__expf(-fabsf(logit)));
        v6[0] = p_ * (fmaxf(-logit, 0.f) + lse);
        v6[1] = n_ * (fmaxf(logit, 0.f) + lse);
        v6[2] = logit >= 0.f ? p_ : 0.f;
        v6[3] = logit < 0.f ? n_ : 0.f;
      }
#pragma unroll
      for (int mask = 1; mask < 16; mask <<= 1) {
#pragma unroll
        for (int qq = 0; qq < 4; ++qq) v6[qq] += __shfl_xor(v6[qq], mask, 64);
      }
      if (tid == 0) {
        int slot = 512 + r * 80 + tile;
        pA[m * PSTRIDE_ + slot] = v6[0];
        pB[m * PSTRIDE_ + slot] = v6[1];
        pPok[m * PSTRIDE_ + slot] = v6[2];
        pNok[m * PSTRIDE_ + slot] = v6[3];
      }
    }
  } else if (bid < 3328) {                // ---------- eval-init ----------
    int q = bid - 2304;
    int m = q >> 9, xb = q & 511;
    float* lea = sbuf;                    // [p=64][t=32][2]
    float* lwb = sbuf + 4096;             // [e=128][{EB,we2}]
    float* red = sbuf + 4352;
    for (int i = tid; i < 4096; i += 256) lea[i] = EA2[m * 4096 + i];
    if (tid < 256) lwb[tid] = EWB[m * 256 + tid];
    __syncthreads();
    int row = xb * 256 + tid;
    int t = thax[row];
    float s = sine[row];
    float acc = 0.f;
#pragma unroll 8
    for (int p = 0; p < 64; ++p) {
      float2 ea = *(const float2*)&lea[(p * 32 + t) * 2];
      float4 wb = *(const float4*)&lwb[p * 4];
      float x0 = fmaf(s, wb.x, ea.x); x0 = fmaxf(x0, 0.f);
      acc = fmaf(x0, wb.y, acc);
      float x1 = fmaf(s, wb.z, ea.y); x1 = fmaxf(x1, 0.f);
      acc = fmaf(x1, wb.w, acc);
    }
    float logit = acc + be2[m] + tweaks[m * 2 + 0];
    float p_ = pos[row], n_ = neg[row];
    float lse = log1pf(__expf(-fabsf(logit)));
    float v[6];
    v[0] = p_ * (fmaxf(-logit, 0.f) + lse);
    v[1] = n_ * (fmaxf(logit, 0.f) + lse);
    v[2] = logit >= 0.f ? p_ : 0.f;
    v[3] = logit < 0.f ? n_ : 0.f;
    v[4] = p_; v[5] = n_;
#pragma unroll
    for (int mask = 1; mask < 64; mask <<= 1) {
#pragma unroll
      for (int k = 0; k < 6; ++k) v[k] += __shfl_xor(v[k], mask, 64);
    }
    if (lane == 0) {
#pragma unroll
      for (int k = 0; k < 6; ++k) red[k * 16 + w] = v[k];
    }
    __syncthreads();
    if (tid == 0) {
      float t6[6];
#pragma unroll
      for (int k = 0; k < 6; ++k)
        t6[k] = red[k * 16 + 0] + red[k * 16 + 1] + red[k * 16 + 2] + red[k * 16 + 3];
      pA[m * PSTRIDE_ + xb] = t6[0];
      pB[m * PSTRIDE_ + xb] = t6[1];
      pPok[m * PSTRIDE_ + xb] = t6[2];
      pNok[m * PSTRIDE_ + xb] = t6[3];
      if (m == 0) { pTp[xb] = t6[4]; pTn[xb] = t6[5]; }
    }
  } else {                                // ---------- deriv pos/neg total ----------
    int j = bid - 3328;                   // 0: pos, 1: neg
    float* red = sbuf;
    const float* src = j ? neg : pos;
    float s = 0.f;
    for (int i = NI_ + tid; i < N_; i += 256) s += src[i];
#pragma unroll
    for (int mask = 1; mask < 64; mask <<= 1) s += __shfl_xor(s, mask, 64);
    if (lane == 0) red[w] = s;
    __syncthreads();
    if (tid == 0) {
      float t = red[0] + red[1] + red[2] + red[3];
      if (j == 0) pTp[1152] = t; else pTn[1152] = t;
    }
  }
}

// ---------------- deterministic final reduction ----------------
__global__ __launch_bounds__(256) void finalize_kernel(
    const float* pA, const float* pB, const float* pPok, const float* pNok,
    const float* pTp, const float* pTn, float* out) {
  __shared__ float lred[10][4];
  const float* srcs[10] = {pA, pA + PSTRIDE_, pB, pB + PSTRIDE_,
                           pPok, pPok + PSTRIDE_, pNok, pNok + PSTRIDE_,
                           pTp, pTn};
  int tid = threadIdx.x;
  int w = tid >> 6, lane = tid & 63;
#pragma unroll
  for (int q = 0; q < 10; ++q) {
    float s = 0.f;
    for (int i = tid; i < PUSED_; i += 256) s += srcs[q][i];
#pragma unroll
    for (int mask = 1; mask < 64; mask <<= 1) s += __shfl_xor(s, mask, 64);
    if (lane == 0) lred[q][w] = s;
  }
  __syncthreads();
  if (tid == 0) {
    float totals[10];
#pragma unroll
    for (int q = 0; q < 10; ++q)
      totals[q] = lred[q][0] + lred[q][1] + lred[q][2] + lred[q][3];
    float tp = totals[8], tn = totals[9];
    float pw = tn / tp;
    out[0] = pw * totals[0] + totals[2];
    out[1] = pw * totals[1] + totals[3];
    out[2] = totals[4]; out[3] = totals[5];
    out[4] = totals[6]; out[5] = totals[7];
    out[6] = tp; out[7] = tn;
  }
}

extern "C" void kernel_launch(void* const* d_in, const int* in_sizes, int n_in,
                              void* d_out, int out_size, void* d_ws, size_t ws_size,
                              hipStream_t stream) {
  const int*   thax = (const int*)d_in[0];
  const float* sine = (const float*)d_in[1];
  const int*   par  = (const int*)d_in[2];
  const int*   ridx = (const int*)d_in[3];
  const float* pos  = (const float*)d_in[4];
  const float* neg  = (const float*)d_in[5];
  const float* init_table = (const float*)d_in[6];
  const float* s_vec = (const float*)d_in[7];
  const float* W1 = (const float*)d_in[8];
  const float* b1 = (const float*)d_in[9];
  const float* W2 = (const float*)d_in[10];
  const float* b2 = (const float*)d_in[11];
  const float* tweaks = (const float*)d_in[12];
  const float* We1 = (const float*)d_in[13];
  const float* be1 = (const float*)d_in[14];
  const float* we2 = (const float*)d_in[15];
  const float* be2 = (const float*)d_in[16];

  char* ws = (char*)d_ws;
  unsigned short* W2T  = (unsigned short*)(ws + OFF_W2T);
  unsigned short* We1T = (unsigned short*)(ws + OFF_WE1T);
  unsigned short* tab  = (unsigned short*)(ws + OFF_TAB);
  unsigned short* svec = (unsigned short*)(ws + OFF_SVEC);
  float* EA2  = (float*)(ws + OFF_EA2);
  float* EWB  = (float*)(ws + OFF_EWB);
  float* pA   = (float*)(ws + OFF_PA);
  float* pB   = (float*)(ws + OFF_PB);
  float* pPok = (float*)(ws + OFF_PPOK);
  float* pNok = (float*)(ws + OFF_PNOK);
  float* pTp  = (float*)(ws + OFF_PTP);
  float* pTn  = (float*)(ws + OFF_PTN);
  float* G    = (float*)(ws + OFF_G);
  int* fastlist = (int*)(ws + OFF_FLIST);
  int* slowlist = (int*)(ws + OFF_SLIST);
  int* cfg      = (int*)(ws + OFF_CFG);

  megaprep_kernel<<<333, 256, 0, stream>>>(
      W1, W2, We1, init_table, s_vec, b1, be1, we2, ridx, par,
      W2T, We1T, tab, svec, G, EA2, EWB,
      fastlist, slowlist, cfg, (unsigned int*)pA);
  main_kernel<<<3330, 256, 0, stream>>>(
      thax, sine, par, ridx, pos, neg, W1, b1, b2, tweaks,
      G, W2T, We1T, tab, svec, EA2, EWB, be1, we2, be2,
      cfg, fastlist, slowlist,
      pA, pB, pPok, pNok, pTp, pTn);
  finalize_kernel<<<1, 256, 0, stream>>>(pA, pB, pPok, pNok, pTp, pTn,
                                         (float*)d_out);
}